// Round 2
// baseline (4489.833 us; speedup 1.0000x reference)
//
#include <hip/hip_runtime.h>
#include <cmath>

#define HH   128
#define G3   384   // 3*H
#define TT   512
#define BTOT 512
#define BB   2                 // batch rows per block
#define NBLK (BTOT / BB)       // 256 blocks -> 1 per CU
#define NTHR 512               // 8 waves -> 2 per SIMD

__device__ __forceinline__ float sigmoidf(float x) {
    return 1.0f / (1.0f + __expf(-x));
}

// One GRU layer. Each block owns BB batch rows and walks t = 0..TT-1
// sequentially (batch rows are independent -> no inter-block sync).
// Thread partition: kt = tid&3 owns a 32-wide k-slice, gt = tid>>2 owns 3
// gate rows; both weight matrices live in registers (2*3*32 = 192 VGPR).
// h lives in LDS; gate phase is threads 0..255 (one per (bb, j)).
template <int INK, bool WRITE_ALL>
__global__ __launch_bounds__(NTHR, 2) void gru_layer(
    const float* in, float* out,                       // may alias (in-place)
    const float* __restrict__ Wih, const float* __restrict__ Whh,
    const float* __restrict__ bih, const float* __restrict__ bhh) {
    const int tid = threadIdx.x;
    const int kt  = tid & 3;
    const int gt  = tid >> 2;   // [0,128)
    const int g0  = gt * 3;
    const int b0  = blockIdx.x * BB;

    __shared__ __align__(16) float s_in[BB][(INK == 5) ? 8 : HH];
    __shared__ __align__(16) float s_h[BB][HH];
    __shared__ float s_xt[BB][G3];
    __shared__ float s_gh[BB][G3];

    // ---- load recurrent weights (3 rows x 32 k) into registers ----
    float wh[3][32];
#pragma unroll
    for (int i = 0; i < 3; ++i) {
        const float* wrow = Whh + (g0 + i) * HH + kt * 32;
#pragma unroll
        for (int j = 0; j < 32; j += 4) {
            float4 v = *(const float4*)(wrow + j);
            wh[i][j] = v.x; wh[i][j + 1] = v.y; wh[i][j + 2] = v.z; wh[i][j + 3] = v.w;
        }
    }
    // ---- input weights ----
    constexpr int KX = (INK == 5) ? 5 : 32;
    float wx[3][KX];
    if (INK == 5) {
        if (kt == 0) {
#pragma unroll
            for (int i = 0; i < 3; ++i)
#pragma unroll
                for (int j = 0; j < 5; ++j) wx[i][j] = Wih[(g0 + i) * 5 + j];
        }
    } else {
#pragma unroll
        for (int i = 0; i < 3; ++i) {
            const float* wrow = Wih + (g0 + i) * INK + kt * 32;
#pragma unroll
            for (int j = 0; j < 32; j += 4) {
                float4 v = *(const float4*)(wrow + j);
                wx[i][j] = v.x; wx[i][j + 1] = v.y; wx[i][j + 2] = v.z; wx[i][j + 3] = v.w;
            }
        }
    }

    // ---- per-gate-thread biases (threads 0..255) ----
    float br = 0.f, bz = 0.f, bxn = 0.f, bhn = 0.f;
    if (tid < BB * HH) {
        int j = tid & (HH - 1);
        br  = bih[j] + bhh[j];
        bz  = bih[HH + j] + bhh[HH + j];
        bxn = bih[2 * HH + j];
        bhn = bhh[2 * HH + j];
    }

    if (tid < BB * HH) s_h[tid >> 7][tid & (HH - 1)] = 0.0f;
    __syncthreads();

    const size_t in_bstride  = (size_t)TT * INK;
    const size_t out_bstride = (size_t)TT * HH;

    for (int t = 0; t < TT; ++t) {
        // ---- phase A: stage x_t (reads in[b][t] BEFORE phase C writes it) ----
        if (INK == 5) {
            if (tid < BB * 5) {
                int bb = tid / 5, k = tid % 5;
                s_in[bb][k] = in[(b0 + bb) * in_bstride + (size_t)t * INK + k];
            }
        } else {
            if (tid < 64) {
                int bb = tid >> 5, k4 = (tid & 31) * 4;
                *(float4*)&s_in[bb][k4] =
                    *(const float4*)&in[(b0 + bb) * in_bstride + (size_t)t * INK + k4];
            }
        }
        __syncthreads();

        // ---- phase B: partial matmuls (registers x LDS-broadcast) ----
        float ax[BB][3], ah[BB][3];
#pragma unroll
        for (int bb = 0; bb < BB; ++bb) {
#pragma unroll
            for (int i = 0; i < 3; ++i) { ax[bb][i] = 0.f; ah[bb][i] = 0.f; }
            const float* hp = &s_h[bb][kt * 32];
#pragma unroll
            for (int jj = 0; jj < 32; jj += 4) {
                float4 hv = *(const float4*)(hp + jj);
#pragma unroll
                for (int i = 0; i < 3; ++i) {
                    ah[bb][i] = fmaf(wh[i][jj + 0], hv.x, ah[bb][i]);
                    ah[bb][i] = fmaf(wh[i][jj + 1], hv.y, ah[bb][i]);
                    ah[bb][i] = fmaf(wh[i][jj + 2], hv.z, ah[bb][i]);
                    ah[bb][i] = fmaf(wh[i][jj + 3], hv.w, ah[bb][i]);
                }
            }
            if (INK == 5) {
                if (kt == 0) {
#pragma unroll
                    for (int i = 0; i < 3; ++i)
#pragma unroll
                        for (int j = 0; j < 5; ++j)
                            ax[bb][i] = fmaf(wx[i][j], s_in[bb][j], ax[bb][i]);
                }
            } else {
                const float* ip = &s_in[bb][kt * 32];
#pragma unroll
                for (int jj = 0; jj < 32; jj += 4) {
                    float4 iv = *(const float4*)(ip + jj);
#pragma unroll
                    for (int i = 0; i < 3; ++i) {
                        ax[bb][i] = fmaf(wx[i][jj + 0], iv.x, ax[bb][i]);
                        ax[bb][i] = fmaf(wx[i][jj + 1], iv.y, ax[bb][i]);
                        ax[bb][i] = fmaf(wx[i][jj + 2], iv.z, ax[bb][i]);
                        ax[bb][i] = fmaf(wx[i][jj + 3], iv.w, ax[bb][i]);
                    }
                }
            }
        }
        // ---- 4-way k-reduction across kt lanes (same wave: lanes differ in bits 0..1)
#pragma unroll
        for (int bb = 0; bb < BB; ++bb)
#pragma unroll
            for (int i = 0; i < 3; ++i) {
                ax[bb][i] += __shfl_xor(ax[bb][i], 1, 64);
                ax[bb][i] += __shfl_xor(ax[bb][i], 2, 64);
                ah[bb][i] += __shfl_xor(ah[bb][i], 1, 64);
                ah[bb][i] += __shfl_xor(ah[bb][i], 2, 64);
            }
        if (kt == 0) {   // static indexing (rule #20): kt==0 writes bb 0
#pragma unroll
            for (int i = 0; i < 3; ++i) { s_xt[0][g0 + i] = ax[0][i]; s_gh[0][g0 + i] = ah[0][i]; }
        } else if (kt == 1) {
#pragma unroll
            for (int i = 0; i < 3; ++i) { s_xt[1][g0 + i] = ax[1][i]; s_gh[1][g0 + i] = ah[1][i]; }
        }
        __syncthreads();

        // ---- phase C: gates + h update (threads 0..255) ----
        if (tid < BB * HH) {
            int bb = tid >> 7, j = tid & (HH - 1);
            float r = sigmoidf(s_xt[bb][j] + s_gh[bb][j] + br);
            float z = sigmoidf(s_xt[bb][HH + j] + s_gh[bb][HH + j] + bz);
            float n = tanhf(s_xt[bb][2 * HH + j] + bxn + r * (s_gh[bb][2 * HH + j] + bhn));
            float hprev = s_h[bb][j];
            float hnew  = (1.0f - z) * n + z * hprev;
            if (WRITE_ALL || t == TT - 1)
                out[(b0 + bb) * out_bstride + (size_t)t * HH + j] = hnew;
            s_h[bb][j] = hnew;
        }
        __syncthreads();
    }
}

// out[b] = dot(h_last[b], fc_w) + fc_b ; one wave per batch row
__global__ __launch_bounds__(256) void fc_kernel(const float* buf,
                                                 const float* __restrict__ fc_w,
                                                 const float* __restrict__ fc_b,
                                                 float* out) {
    int wave = threadIdx.x >> 6, lane = threadIdx.x & 63;
    int b = blockIdx.x * 4 + wave;
    const float* h = buf + ((size_t)b * TT + (TT - 1)) * HH;
    float s = h[lane] * fc_w[lane] + h[lane + 64] * fc_w[lane + 64];
#pragma unroll
    for (int m = 32; m >= 1; m >>= 1) s += __shfl_xor(s, m, 64);
    if (lane == 0) out[b] = s + fc_b[0];
}

extern "C" void kernel_launch(void* const* d_in, const int* in_sizes, int n_in,
                              void* d_out, int out_size, void* d_ws, size_t ws_size,
                              hipStream_t stream) {
    const float* x    = (const float*)d_in[0];
    const float* Wih0 = (const float*)d_in[1];
    const float* Whh0 = (const float*)d_in[2];
    const float* bih0 = (const float*)d_in[3];
    const float* bhh0 = (const float*)d_in[4];
    const float* WihR = (const float*)d_in[5];
    const float* WhhR = (const float*)d_in[6];
    const float* bihR = (const float*)d_in[7];
    const float* bhhR = (const float*)d_in[8];
    const float* fcw  = (const float*)d_in[9];
    const float* fcb  = (const float*)d_in[10];

    float* buf = (float*)d_ws;  // 512*512*128*4 = 134,217,728 bytes (in-place per layer)

    gru_layer<5, true><<<NBLK, NTHR, 0, stream>>>(x, buf, Wih0, Whh0, bih0, bhh0);
    gru_layer<128, true><<<NBLK, NTHR, 0, stream>>>(buf, buf, WihR, WhhR, bihR, bhhR);
    gru_layer<128, true><<<NBLK, NTHR, 0, stream>>>(buf, buf, WihR + G3 * HH, WhhR + G3 * HH,
                                                    bihR + G3, bhhR + G3);
    gru_layer<128, false><<<NBLK, NTHR, 0, stream>>>(buf, buf, WihR + 2 * G3 * HH,
                                                     WhhR + 2 * G3 * HH, bihR + 2 * G3,
                                                     bhhR + 2 * G3);
    fc_kernel<<<BTOT / 4, 256, 0, stream>>>(buf, fcw, fcb, (float*)d_out);
}